// Round 7
// baseline (242.010 us; speedup 1.0000x reference)
//
#include <hip/hip_runtime.h>

#define BB 16
#define HH 256
#define WW 256
#define CC 32
#define C1 4

#if __has_builtin(__builtin_amdgcn_mfma_i32_32x32x32_i8)
#define K32 1
#else
#define K32 0
#endif

typedef int i32x4 __attribute__((ext_vector_type(4)));
typedef int i32x16 __attribute__((ext_vector_type(16)));

// ---- weight quantization ----
__global__ void qw1_kernel(const float* __restrict__ w, float* __restrict__ out) {
  int i = blockIdx.x * blockDim.x + threadIdx.x;
  if (i >= 32 * 4 * 9) return;
  float k = rintf(w[i] * 128.0f);
  k = fminf(127.0f, fmaxf(-127.0f, k));
  out[i] = k * 0.0078125f;  // keep OIHW, as float k/128
}

// OIHW fp32 -> per-lane MFMA fragments (int8); lane map row/col = l&31,
// k = (l>>5)*16 + j (same formula for A and B operands).
__global__ void qw_frag_kernel(const float* __restrict__ w, signed char* __restrict__ frag) {
  int i = blockIdx.x * blockDim.x + threadIdx.x;
  if (i >= 9216) return;
#if K32
  int t = i >> 10;
  int l = (i >> 4) & 63;
  int j = i & 15;
  int ic = (l >> 5) * 16 + j;
#else
  int s = i >> 9;
  int l = (i >> 3) & 63;
  int j = i & 7;
  int t = s >> 1;
  int ic = (s & 1) * 16 + (l >> 5) * 8 + j;
#endif
  int oc = l & 31;
  int q = (int)rintf(w[oc * 288 + ic * 9 + t] * 128.0f);
  q = min(127, max(-127, q));
  frag[i] = (signed char)q;
}

__global__ void qwfc_kernel(const float* __restrict__ w, int* __restrict__ out) {
  int i = threadIdx.x;
  if (i < 32) {
    int q = (int)rintf(w[i] * 128.0f);
    q = min(127, max(-127, q));
    out[i] = q;
  }
}

__global__ void initmax_kernel(int* __restrict__ gmax) {
  int i = threadIdx.x;
  if (i < 512) gmax[i] = -128;
}

// ---- conv1: fp32 NCHW input (Cin=4) -> int8 NHWC ----
// launch_bounds(256,2): stop the VGPR-28 spill seen in rounds 4/6.
// 1-D grid 4096, XCD-chunked: XCD c handles batches {2c, 2c+1}.
__global__ __launch_bounds__(256, 2) void conv1_kernel(
    const float* __restrict__ x, const float* __restrict__ w1q,
    signed char* __restrict__ out) {
  int tid = threadIdx.x;
  int bid = blockIdx.x;
  int wg = (bid & 7) * 512 + (bid >> 3);
  int b = wg >> 8;
  int rem = wg & 255;
  int h = (rem >> 4) * 16 + (tid >> 4);
  int w = (rem & 15) * 16 + (tid & 15);

  float v[36];
#pragma unroll
  for (int ic = 0; ic < C1; ++ic)
#pragma unroll
    for (int dy = 0; dy < 3; ++dy) {
      int yy = h + dy - 1;
#pragma unroll
      for (int dx = 0; dx < 3; ++dx) {
        int xx = w + dx - 1;
        bool ok = ((unsigned)yy < 256u) && ((unsigned)xx < 256u);
        v[ic * 9 + dy * 3 + dx] = ok ? x[(((size_t)b * C1 + ic) * HH + yy) * WW + xx] : 0.0f;
      }
    }

  int ow[8];
#pragma unroll
  for (int og = 0; og < 8; ++og) {
    int packed = 0;
#pragma unroll
    for (int oj = 0; oj < 4; ++oj) {
      int oc = og * 4 + oj;
      float acc = 0.0f;
      const float* wp = &w1q[oc * 36];
#pragma unroll
      for (int i = 0; i < 36; ++i) acc += v[i] * wp[i];  // same order as reference
      int q = (int)rintf(acc * 128.0f);
      q = min(127, max(-127, q));
      packed |= (q & 0xff) << (8 * oj);
    }
    ow[og] = packed;
  }
  signed char* op = out + (((size_t)b * HH + h) * WW + w) * CC;
  ((int4*)op)[0] = make_int4(ow[0], ow[1], ow[2], ow[3]);
  ((int4*)op)[1] = make_int4(ow[4], ow[5], ow[6], ow[7]);
}

__device__ __forceinline__ int quant1(int a) {
  int q = (int)rintf((float)a * 0.0078125f);  // rne(acc/128), exact in fp32
  return min(127, max(-127, q));
}

__device__ __forceinline__ int quant_max(const i32x16& acc, int mymax) {
#pragma unroll
  for (int r = 0; r < 16; ++r) mymax = max(mymax, quant1(acc[r]));
  return mymax;
}

// ---- conv layers 2..7: implicit-GEMM via i8 MFMA, 2 output rows per wave ----
// Mid layers use swapped operands (A=weights, B=activations) so D is
// [oc][px] with px = lane&31 -> epilogue packs dwords, 8 dword stores.
// LAST keeps A=activations (col=oc) for the cheap per-oc max reduce.
template <bool LAST>
__global__ __launch_bounds__(256, 2) void conv_mfma_kernel_t(
    const signed char* __restrict__ in, const signed char* __restrict__ frag,
    signed char* __restrict__ out, int* __restrict__ gmax) {
  __shared__ int red[4][32];
  int tid = threadIdx.x;
  int wi = tid >> 6;
  int l = tid & 63;
  int lo = l & 31;
  int hi = l >> 5;
  int bid = blockIdx.x;
  int wg = (bid & 7) * 512 + (bid >> 3);  // XCD-chunked: XCD c -> batches 2c,2c+1
  int b = wg >> 8;
  int rem = wg & 255;
  int h0 = (rem >> 1) * 2;           // output rows h0, h0+1
  int wbase = (rem & 1) * 128 + wi * 32;
  int w = wbase + lo;

  const size_t img = (size_t)b * (HH * WW);
  i32x16 acc0 = {}, acc1 = {};

#if K32
  i32x4 bf[9];
  const i32x4* fp = (const i32x4*)frag;
#pragma unroll
  for (int s = 0; s < 9; ++s) bf[s] = fp[s * 64 + l];

#pragma unroll
  for (int row = 0; row < 4; ++row) {  // input rows h0-1 .. h0+2
    int yy = h0 - 1 + row;
    bool okrow = (unsigned)yy < 256u;
#pragma unroll
    for (int dx = 0; dx < 3; ++dx) {
      int xx = w + dx - 1;
      i32x4 av = {};
      if (okrow && ((unsigned)xx < 256u))
        av = *(const i32x4*)(in + ((img + (size_t)yy * WW + xx) << 5) + hi * 16);
      if (LAST) {
        if (row < 3) acc0 = __builtin_amdgcn_mfma_i32_32x32x32_i8(av, bf[row * 3 + dx], acc0, 0, 0, 0);
        if (row > 0) acc1 = __builtin_amdgcn_mfma_i32_32x32x32_i8(av, bf[(row - 1) * 3 + dx], acc1, 0, 0, 0);
      } else {
        if (row < 3) acc0 = __builtin_amdgcn_mfma_i32_32x32x32_i8(bf[row * 3 + dx], av, acc0, 0, 0, 0);
        if (row > 0) acc1 = __builtin_amdgcn_mfma_i32_32x32x32_i8(bf[(row - 1) * 3 + dx], av, acc1, 0, 0, 0);
      }
    }
  }
#else
  long bf[18];
  const long* fp = (const long*)frag;
#pragma unroll
  for (int s = 0; s < 18; ++s) bf[s] = fp[s * 64 + l];

#pragma unroll
  for (int row = 0; row < 4; ++row) {
    int yy = h0 - 1 + row;
    bool okrow = (unsigned)yy < 256u;
#pragma unroll
    for (int dx = 0; dx < 3; ++dx) {
      int xx = w + dx - 1;
#pragma unroll
      for (int s2 = 0; s2 < 2; ++s2) {
        long av = 0;
        if (okrow && ((unsigned)xx < 256u))
          av = *(const long*)(in + ((img + (size_t)yy * WW + xx) << 5) + s2 * 16 + hi * 8);
        if (LAST) {
          if (row < 3)
            acc0 = __builtin_amdgcn_mfma_i32_32x32x16_i8(av, bf[(row * 3 + dx) * 2 + s2], acc0, 0, 0, 0);
          if (row > 0)
            acc1 = __builtin_amdgcn_mfma_i32_32x32x16_i8(av, bf[((row - 1) * 3 + dx) * 2 + s2], acc1, 0, 0, 0);
        } else {
          if (row < 3)
            acc0 = __builtin_amdgcn_mfma_i32_32x32x16_i8(bf[(row * 3 + dx) * 2 + s2], av, acc0, 0, 0, 0);
          if (row > 0)
            acc1 = __builtin_amdgcn_mfma_i32_32x32x16_i8(bf[((row - 1) * 3 + dx) * 2 + s2], av, acc1, 0, 0, 0);
        }
      }
    }
  }
#endif

  if (!LAST) {
    // D[oc][px]: lane holds px = wbase+lo, ocs = (r&3)+8*(r>>2)+4*hi.
    // dword d (regs 4d..4d+3) = ocs 8d+4hi+{0..3} -> NHWC byte off 8d+4hi.
    int* o32 = (int*)(out + ((img + (size_t)h0 * WW + wbase) << 5));
#pragma unroll
    for (int d = 0; d < 4; ++d) {
      int q0 = quant1(acc0[4 * d]), q1 = quant1(acc0[4 * d + 1]);
      int q2 = quant1(acc0[4 * d + 2]), q3 = quant1(acc0[4 * d + 3]);
      o32[lo * 8 + 2 * d + hi] =
          (q0 & 255) | ((q1 & 255) << 8) | ((q2 & 255) << 16) | ((q3 & 255) << 24);
    }
    int* o32b = o32 + WW * 8;
#pragma unroll
    for (int d = 0; d < 4; ++d) {
      int q0 = quant1(acc1[4 * d]), q1 = quant1(acc1[4 * d + 1]);
      int q2 = quant1(acc1[4 * d + 2]), q3 = quant1(acc1[4 * d + 3]);
      o32b[lo * 8 + 2 * d + hi] =
          (q0 & 255) | ((q1 & 255) << 8) | ((q2 & 255) << 16) | ((q3 & 255) << 24);
    }
  } else {
    int mymax = quant_max(acc1, quant_max(acc0, -128));
    mymax = max(mymax, __shfl_xor(mymax, 32));
    if (hi == 0) red[wi][lo] = mymax;
    __syncthreads();
    if (tid < 32) {
      int m = max(max(red[0][tid], red[1][tid]), max(red[2][tid], red[3][tid]));
      atomicMax(&gmax[b * 32 + tid], m);
    }
  }
}

// ---- final FC over per-(b,oc) maxes ----
__global__ void fc_kernel(const int* __restrict__ gmax, const int* __restrict__ wfcq,
                          float* __restrict__ out) {
  int b = threadIdx.x;
  if (b < BB) {
    int acc = 0;
#pragma unroll
    for (int c = 0; c < 32; ++c) acc += gmax[b * 32 + c] * wfcq[c];
    int q = (int)rintf((float)acc * 0.0078125f);  // rne(acc/128), exact
    q = min(127, max(-127, q));
    out[b] = (float)q * 0.0078125f;
  }
}

extern "C" void kernel_launch(void* const* d_in, const int* in_sizes, int n_in,
                              void* d_out, int out_size, void* d_ws, size_t ws_size,
                              hipStream_t stream) {
  const float* x   = (const float*)d_in[0];
  const float* w1  = (const float*)d_in[1];
  const float* wfc = (const float*)d_in[8];

  char* ws = (char*)d_ws;
  const size_t ACT = (size_t)BB * HH * WW * CC;  // 33,554,432 B
  signed char* A0   = (signed char*)ws;
  signed char* A1   = (signed char*)(ws + ACT);
  float*       w1q  = (float*)(ws + 2 * ACT);
  signed char* wfr  = (signed char*)(ws + 2 * ACT + 4608);        // 6 x 9216
  int*         wfcq = (int*)(ws + 2 * ACT + 4608 + 6 * 9216);
  int*         gmax = (int*)(ws + 2 * ACT + 4608 + 6 * 9216 + 128);

  qw1_kernel<<<5, 256, 0, stream>>>(w1, w1q);
  for (int l = 0; l < 6; ++l)
    qw_frag_kernel<<<36, 256, 0, stream>>>((const float*)d_in[2 + l], wfr + l * 9216);
  qwfc_kernel<<<1, 64, 0, stream>>>(wfc, wfcq);
  initmax_kernel<<<1, 512, 0, stream>>>(gmax);

  conv1_kernel<<<4096, 256, 0, stream>>>(x, w1q, A0);

  signed char* pin = A0;
  signed char* pout = A1;
  for (int l = 0; l < 5; ++l) {
    conv_mfma_kernel_t<false><<<4096, 256, 0, stream>>>(pin, wfr + l * 9216, pout, nullptr);
    signed char* t = pin; pin = pout; pout = t;
  }
  conv_mfma_kernel_t<true><<<4096, 256, 0, stream>>>(pin, wfr + 5 * 9216, nullptr, gmax);
  fc_kernel<<<1, 64, 0, stream>>>(gmax, wfcq, (float*)d_out);
}

// Round 8
// 188.917 us; speedup vs baseline: 1.2810x; 1.2810x over previous
//
#include <hip/hip_runtime.h>

#define BB 16
#define HH 256
#define WW 256
#define CC 32
#define C1 4

#if __has_builtin(__builtin_amdgcn_mfma_i32_32x32x32_i8)
#define K32 1
#else
#define K32 0
#endif

typedef int i32x4 __attribute__((ext_vector_type(4)));
typedef int i32x16 __attribute__((ext_vector_type(16)));
typedef float f32x16 __attribute__((ext_vector_type(16)));
typedef _Float16 f16x8 __attribute__((ext_vector_type(8)));

// ================= fused prep =================
// blocks [0,4096):    x (fp32 NCHW) -> pre (NHWC f16 hi/lo pairs, 16B/px)
// blocks [4096,4312): 6 mid-layer int8 weight frags
// block 4312:         conv1 f16 B-frags, wfc quant, gmax init
__global__ __launch_bounds__(256) void prep_kernel(
    const float* __restrict__ x, const float* __restrict__ w1,
    const float* __restrict__ w2, const float* __restrict__ w3,
    const float* __restrict__ w4, const float* __restrict__ w5,
    const float* __restrict__ w6, const float* __restrict__ w7,
    const float* __restrict__ wfc,
    _Float16* __restrict__ pre, _Float16* __restrict__ frag1,
    signed char* __restrict__ wfr, int* __restrict__ wfcq,
    int* __restrict__ gmax) {
  int bid = blockIdx.x, tid = threadIdx.x;
  if (bid < 4096) {
    int px = bid * 256 + tid;  // 1,048,576 pixels
    int b = px >> 16, rem = px & 65535;
    const float* xp = x + (size_t)b * 4 * 65536 + rem;
    f16x8 o;
#pragma unroll
    for (int ic = 0; ic < 4; ++ic) {
      float v = xp[ic * 65536];
      _Float16 hf = (_Float16)v;
      float r = v - (float)hf;
      o[ic * 2] = hf;
      o[ic * 2 + 1] = (_Float16)r;
    }
    *(f16x8*)(pre + (size_t)px * 8) = o;
  } else if (bid < 4312) {
    int i = (bid - 4096) * 256 + tid;  // 6 x 9216
    int layer = i / 9216, within = i - layer * 9216;
    const float* w = layer == 0 ? w2 : layer == 1 ? w3 : layer == 2 ? w4
                   : layer == 3 ? w5 : layer == 4 ? w6 : w7;
#if K32
    int t = within >> 10;
    int l = (within >> 4) & 63;
    int j = within & 15;
    int ic = (l >> 5) * 16 + j;
#else
    int s = within >> 9;
    int l = (within >> 3) & 63;
    int j = within & 7;
    int t = s >> 1;
    int ic = (s & 1) * 16 + (l >> 5) * 8 + j;
#endif
    int oc = l & 31;
    int q = (int)rintf(w[oc * 288 + ic * 9 + t] * 128.0f);
    q = min(127, max(-127, q));
    wfr[(size_t)layer * 9216 + within] = (signed char)q;
  } else {
    // conv1 B-frags: slot s = dy*2+p; lane l: oc=l&31, half=l>>5; j: ic=j>>1
    // (weight duplicated over hi/lo slots); pad slot (p==1,half==1) = 0.
    for (int p = tid; p < 384; p += 256) {
      int s = p >> 6, l = p & 63;
      int dr = s >> 1, pp = s & 1;
      int oc = l & 31, half = l >> 5;
      int dx = pp * 2 + half;
#pragma unroll
      for (int j = 0; j < 8; ++j) {
        int ic = j >> 1;
        _Float16 v = (_Float16)0.f;
        if (!(pp == 1 && half == 1)) {
          int q = (int)rintf(w1[oc * 36 + ic * 9 + dr * 3 + dx] * 128.0f);
          q = min(127, max(-127, q));
          v = (_Float16)((float)q * 0.0078125f);  // exact in fp16
        }
        frag1[s * 512 + l * 8 + j] = v;
      }
    }
    if (tid < 32) {
      int q = (int)rintf(wfc[tid] * 128.0f);
      q = min(127, max(-127, q));
      wfcq[tid] = q;
    }
    for (int i2 = tid; i2 < 512; i2 += 256) gmax[i2] = -128;
  }
}

// ================= conv1: f16 hi/lo implicit-GEMM MFMA =================
// Same structure as mid layers: 2 output rows/wave, 32 px x 32 oc, K=96
// (6 slots x 16; slot = (dy, dx-pair), k within = ic*2 + {hi,lo}).
__global__ __launch_bounds__(256) void conv1_mfma_kernel(
    const _Float16* __restrict__ pre, const _Float16* __restrict__ frag1,
    signed char* __restrict__ out) {
  int tid = threadIdx.x;
  int wi = tid >> 6;
  int l = tid & 63;
  int lo = l & 31;
  int hi = l >> 5;
  int b = blockIdx.z;
  int h0 = blockIdx.y * 2;
  int wbase = blockIdx.x * 128 + wi * 32;
  int w = wbase + lo;

  const f16x8* fp = (const f16x8*)frag1;
  f16x8 bf[6];
#pragma unroll
  for (int s = 0; s < 6; ++s) bf[s] = fp[s * 64 + l];

  f32x16 acc0 = {}, acc1 = {};
  const size_t img = (size_t)b * (HH * WW);

#pragma unroll
  for (int r = 0; r < 4; ++r) {  // input rows h0-1 .. h0+2
    int yy = h0 - 1 + r;
    bool okr = (unsigned)yy < 256u;
#pragma unroll
    for (int p = 0; p < 2; ++p) {
      int xx = w + p * 2 + hi - 1;  // dx = 2p + half
      f16x8 av = {};
      if (okr && !(p == 1 && hi == 1) && ((unsigned)xx < 256u))
        av = *(const f16x8*)(pre + ((img + (size_t)yy * WW + xx) << 3));
      if (r < 3) acc0 = __builtin_amdgcn_mfma_f32_32x32x16_f16(av, bf[r * 2 + p], acc0, 0, 0, 0);
      if (r > 0) acc1 = __builtin_amdgcn_mfma_f32_32x32x16_f16(av, bf[(r - 1) * 2 + p], acc1, 0, 0, 0);
    }
  }

  // D: col(oc)=lane&31, row(px)=(r&3)+8*(r>>2)+4*(lane>>5) — same as i8 path
  signed char* op = out + ((img + (size_t)h0 * WW + wbase) << 5) + lo;
#pragma unroll
  for (int r = 0; r < 16; ++r) {
    int row = (r & 3) + 8 * (r >> 2) + 4 * hi;
    int q0 = (int)rintf(acc0[r] * 128.0f);
    q0 = min(127, max(-127, q0));
    op[row * 32] = (signed char)q0;
    int q1 = (int)rintf(acc1[r] * 128.0f);
    q1 = min(127, max(-127, q1));
    op[WW * 32 + row * 32] = (signed char)q1;
  }
}

// ================= mid/last convs (round-6 form, exact int8) =================
__device__ __forceinline__ void quant_store(const i32x16& acc, signed char* op, int hi) {
#pragma unroll
  for (int r = 0; r < 16; ++r) {
    int row = (r & 3) + 8 * (r >> 2) + 4 * hi;
    int q = (int)rintf((float)acc[r] * 0.0078125f);  // rne(acc/128), exact
    q = min(127, max(-127, q));
    op[row * 32] = (signed char)q;
  }
}

__device__ __forceinline__ int quant_max(const i32x16& acc, int mymax) {
#pragma unroll
  for (int r = 0; r < 16; ++r) {
    int q = (int)rintf((float)acc[r] * 0.0078125f);
    q = min(127, max(-127, q));
    mymax = max(mymax, q);
  }
  return mymax;
}

template <bool LAST>
__global__ __launch_bounds__(256) void conv_mfma_kernel_t(
    const signed char* __restrict__ in, const signed char* __restrict__ frag,
    signed char* __restrict__ out, int* __restrict__ gmax) {
  __shared__ int red[4][32];
  int tid = threadIdx.x;
  int wi = tid >> 6;
  int l = tid & 63;
  int lo = l & 31;
  int hi = l >> 5;
  int b = blockIdx.z;
  int h0 = blockIdx.y * 2;  // output rows h0, h0+1
  int wbase = blockIdx.x * 128 + wi * 32;
  int w = wbase + lo;

  const size_t img = (size_t)b * (HH * WW);
  i32x16 acc0 = {}, acc1 = {};

#if K32
  i32x4 bf[9];
  const i32x4* fp = (const i32x4*)frag;
#pragma unroll
  for (int s = 0; s < 9; ++s) bf[s] = fp[s * 64 + l];

#pragma unroll
  for (int row = 0; row < 4; ++row) {  // input rows h0-1 .. h0+2
    int yy = h0 - 1 + row;
    bool okrow = (unsigned)yy < 256u;
#pragma unroll
    for (int dx = 0; dx < 3; ++dx) {
      int xx = w + dx - 1;
      i32x4 av = {};
      if (okrow && ((unsigned)xx < 256u))
        av = *(const i32x4*)(in + ((img + (size_t)yy * WW + xx) << 5) + hi * 16);
      if (row < 3) acc0 = __builtin_amdgcn_mfma_i32_32x32x32_i8(av, bf[row * 3 + dx], acc0, 0, 0, 0);
      if (row > 0) acc1 = __builtin_amdgcn_mfma_i32_32x32x32_i8(av, bf[(row - 1) * 3 + dx], acc1, 0, 0, 0);
    }
  }
#else
  long bf[18];
  const long* fp = (const long*)frag;
#pragma unroll
  for (int s = 0; s < 18; ++s) bf[s] = fp[s * 64 + l];

#pragma unroll
  for (int row = 0; row < 4; ++row) {
    int yy = h0 - 1 + row;
    bool okrow = (unsigned)yy < 256u;
#pragma unroll
    for (int dx = 0; dx < 3; ++dx) {
      int xx = w + dx - 1;
#pragma unroll
      for (int s2 = 0; s2 < 2; ++s2) {
        long av = 0;
        if (okrow && ((unsigned)xx < 256u))
          av = *(const long*)(in + ((img + (size_t)yy * WW + xx) << 5) + s2 * 16 + hi * 8);
        if (row < 3)
          acc0 = __builtin_amdgcn_mfma_i32_32x32x16_i8(av, bf[(row * 3 + dx) * 2 + s2], acc0, 0, 0, 0);
        if (row > 0)
          acc1 = __builtin_amdgcn_mfma_i32_32x32x16_i8(av, bf[((row - 1) * 3 + dx) * 2 + s2], acc1, 0, 0, 0);
      }
    }
  }
#endif

  if (!LAST) {
    signed char* op0 = out + ((img + (size_t)h0 * WW + wbase) << 5) + lo;
    quant_store(acc0, op0, hi);
    quant_store(acc1, op0 + ((size_t)WW << 5), hi);
  } else {
    int mymax = quant_max(acc1, quant_max(acc0, -128));
    mymax = max(mymax, __shfl_xor(mymax, 32));
    if (hi == 0) red[wi][lo] = mymax;
    __syncthreads();
    if (tid < 32) {
      int m = max(max(red[0][tid], red[1][tid]), max(red[2][tid], red[3][tid]));
      atomicMax(&gmax[b * 32 + tid], m);
    }
  }
}

// ================= final FC =================
__global__ void fc_kernel(const int* __restrict__ gmax, const int* __restrict__ wfcq,
                          float* __restrict__ out) {
  int b = threadIdx.x;
  if (b < BB) {
    int acc = 0;
#pragma unroll
    for (int c = 0; c < 32; ++c) acc += gmax[b * 32 + c] * wfcq[c];
    int q = (int)rintf((float)acc * 0.0078125f);  // rne(acc/128), exact
    q = min(127, max(-127, q));
    out[b] = (float)q * 0.0078125f;
  }
}

extern "C" void kernel_launch(void* const* d_in, const int* in_sizes, int n_in,
                              void* d_out, int out_size, void* d_ws, size_t ws_size,
                              hipStream_t stream) {
  const float* x   = (const float*)d_in[0];
  const float* w1  = (const float*)d_in[1];
  const float* wfc = (const float*)d_in[8];

  char* ws = (char*)d_ws;
  const size_t ACT = (size_t)BB * HH * WW * CC;  // 33,554,432 B
  signed char* A0    = (signed char*)ws;
  signed char* A1    = (signed char*)(ws + ACT);
  _Float16*    pre   = (_Float16*)A1;  // 16.8 MB, dead before layer-2 writes A1
  _Float16*    frag1 = (_Float16*)(ws + 2 * ACT);                 // 6144 B
  signed char* wfr   = (signed char*)(ws + 2 * ACT + 6144);       // 6 x 9216
  int*         wfcq  = (int*)(ws + 2 * ACT + 6144 + 6 * 9216);
  int*         gmax  = (int*)(ws + 2 * ACT + 6144 + 6 * 9216 + 128);

  prep_kernel<<<4313, 256, 0, stream>>>(
      x, w1, (const float*)d_in[2], (const float*)d_in[3], (const float*)d_in[4],
      (const float*)d_in[5], (const float*)d_in[6], (const float*)d_in[7],
      wfc, pre, frag1, wfr, wfcq, gmax);

  dim3 gridc(2, 128, 16);  // x: 128-px strip, y: 2-row pair, z: batch
  conv1_mfma_kernel<<<gridc, 256, 0, stream>>>(pre, frag1, A0);

  signed char* pin = A0;
  signed char* pout = A1;
  for (int l = 0; l < 5; ++l) {
    conv_mfma_kernel_t<false><<<gridc, 256, 0, stream>>>(pin, wfr + l * 9216, pout, nullptr);
    signed char* t = pin; pin = pout; pout = t;
  }
  conv_mfma_kernel_t<true><<<gridc, 256, 0, stream>>>(pin, wfr + 5 * 9216, nullptr, gmax);
  fc_kernel<<<1, 64, 0, stream>>>(gmax, wfcq, (float*)d_out);
}

// Round 10
// 183.787 us; speedup vs baseline: 1.3168x; 1.0279x over previous
//
#include <hip/hip_runtime.h>

#define BB 16
#define HH 256
#define WW 256
#define CC 32
#define C1 4

#if __has_builtin(__builtin_amdgcn_mfma_i32_32x32x32_i8)
#define K32 1
#else
#define K32 0
#endif

typedef int i32x4 __attribute__((ext_vector_type(4)));
typedef int i32x16 __attribute__((ext_vector_type(16)));
typedef float f32x16 __attribute__((ext_vector_type(16)));
typedef _Float16 f16x8 __attribute__((ext_vector_type(8)));

// ================= fused prep =================
__global__ __launch_bounds__(256) void prep_kernel(
    const float* __restrict__ x, const float* __restrict__ w1,
    const float* __restrict__ w2, const float* __restrict__ w3,
    const float* __restrict__ w4, const float* __restrict__ w5,
    const float* __restrict__ w6, const float* __restrict__ w7,
    const float* __restrict__ wfc,
    _Float16* __restrict__ pre, _Float16* __restrict__ frag1,
    signed char* __restrict__ wfr, int* __restrict__ wfcq,
    int* __restrict__ gmax) {
  int bid = blockIdx.x, tid = threadIdx.x;
  if (bid < 4096) {
    int px = bid * 256 + tid;  // 1,048,576 pixels
    int b = px >> 16, rem = px & 65535;
    const float* xp = x + (size_t)b * 4 * 65536 + rem;
    f16x8 o;
#pragma unroll
    for (int ic = 0; ic < 4; ++ic) {
      float v = xp[ic * 65536];
      _Float16 hf = (_Float16)v;
      float r = v - (float)hf;
      o[ic * 2] = hf;
      o[ic * 2 + 1] = (_Float16)r;
    }
    *(f16x8*)(pre + (size_t)px * 8) = o;
  } else if (bid < 4312) {
    int i = (bid - 4096) * 256 + tid;  // 6 x 9216
    int layer = i / 9216, within = i - layer * 9216;
    const float* w = layer == 0 ? w2 : layer == 1 ? w3 : layer == 2 ? w4
                   : layer == 3 ? w5 : layer == 4 ? w6 : w7;
#if K32
    int t = within >> 10;
    int l = (within >> 4) & 63;
    int j = within & 15;
    int ic = (l >> 5) * 16 + j;
#else
    int s = within >> 9;
    int l = (within >> 3) & 63;
    int j = within & 7;
    int t = s >> 1;
    int ic = (s & 1) * 16 + (l >> 5) * 8 + j;
#endif
    int oc = l & 31;
    int q = (int)rintf(w[oc * 288 + ic * 9 + t] * 128.0f);
    q = min(127, max(-127, q));
    wfr[(size_t)layer * 9216 + within] = (signed char)q;
  } else {
    // conv1 f16 B-frags
    for (int p = tid; p < 384; p += 256) {
      int s = p >> 6, l = p & 63;
      int dr = s >> 1, pp = s & 1;
      int oc = l & 31, half = l >> 5;
      int dx = pp * 2 + half;
#pragma unroll
      for (int j = 0; j < 8; ++j) {
        int ic = j >> 1;
        _Float16 v = (_Float16)0.f;
        if (!(pp == 1 && half == 1)) {
          int q = (int)rintf(w1[oc * 36 + ic * 9 + dr * 3 + dx] * 128.0f);
          q = min(127, max(-127, q));
          v = (_Float16)((float)q * 0.0078125f);  // exact in fp16
        }
        frag1[s * 512 + l * 8 + j] = v;
      }
    }
    if (tid < 32) {
      int q = (int)rintf(wfc[tid] * 128.0f);
      q = min(127, max(-127, q));
      wfcq[tid] = q;
    }
    for (int i2 = tid; i2 < 512; i2 += 256) gmax[i2] = -128;
  }
}

// ================= conv1: f16 hi/lo implicit-GEMM MFMA =================
__global__ __launch_bounds__(256) void conv1_mfma_kernel(
    const _Float16* __restrict__ pre, const _Float16* __restrict__ frag1,
    signed char* __restrict__ out) {
  int tid = threadIdx.x;
  int wi = tid >> 6;
  int l = tid & 63;
  int lo = l & 31;
  int hi = l >> 5;
  int b = blockIdx.z;
  int h0 = blockIdx.y * 2;
  int wbase = blockIdx.x * 128 + wi * 32;
  int w = wbase + lo;

  const f16x8* fp = (const f16x8*)frag1;
  f16x8 bf[6];
#pragma unroll
  for (int s = 0; s < 6; ++s) bf[s] = fp[s * 64 + l];

  f32x16 acc0 = {}, acc1 = {};
  const size_t img = (size_t)b * (HH * WW);

#pragma unroll
  for (int r = 0; r < 4; ++r) {  // input rows h0-1 .. h0+2
    int yy = h0 - 1 + r;
    bool okr = (unsigned)yy < 256u;
#pragma unroll
    for (int p = 0; p < 2; ++p) {
      int xx = w + p * 2 + hi - 1;  // dx = 2p + half
      f16x8 av = {};
      if (okr && !(p == 1 && hi == 1) && ((unsigned)xx < 256u))
        av = *(const f16x8*)(pre + ((img + (size_t)yy * WW + xx) << 3));
      if (r < 3) acc0 = __builtin_amdgcn_mfma_f32_32x32x16_f16(av, bf[r * 2 + p], acc0, 0, 0, 0);
      if (r > 0) acc1 = __builtin_amdgcn_mfma_f32_32x32x16_f16(av, bf[(r - 1) * 2 + p], acc1, 0, 0, 0);
    }
  }

  signed char* op = out + ((img + (size_t)h0 * WW + wbase) << 5) + lo;
#pragma unroll
  for (int r = 0; r < 16; ++r) {
    int row = (r & 3) + 8 * (r >> 2) + 4 * hi;
    int q0 = (int)rintf(acc0[r] * 128.0f);
    q0 = min(127, max(-127, q0));
    op[row * 32] = (signed char)q0;
    int q1 = (int)rintf(acc1[r] * 128.0f);
    q1 = min(127, max(-127, q1));
    op[WW * 32 + row * 32] = (signed char)q1;
  }
}

// ================= mid/last convs =================
__device__ __forceinline__ int quant1(int a) {
  int q = (int)rintf((float)a * 0.0078125f);  // rne(acc/128), exact in fp32
  return min(127, max(-127, q));
}

__device__ __forceinline__ int quant_max(const i32x16& acc, int mymax) {
#pragma unroll
  for (int r = 0; r < 16; ++r) mymax = max(mymax, quant1(acc[r]));
  return mymax;
}

__device__ __forceinline__ int pack4(int q0, int q1, int q2, int q3) {
  return (q0 & 255) | ((q1 & 255) << 8) | ((q2 & 255) << 16) | ((q3 & 255) << 24);
}

// Mid layers: swapped operands (A=weights) -> lane owns one pixel (px=lane&31),
// oc = (r&3)+8*(r>>2)+4*hi (verified bit-exact in round 7). Epilogue stages
// packed dwords in LDS, then stores fully coalesced int4 per thread.
// LAST: A=activations (col=oc) for the cheap per-oc max reduce; no store.
template <bool LAST>
__global__ __launch_bounds__(256) void conv_mfma_kernel_t(
    const signed char* __restrict__ in, const signed char* __restrict__ frag,
    signed char* __restrict__ out, int* __restrict__ gmax) {
  __shared__ int red[4][32];
  __shared__ int tr[2048];  // [2 rows][128 px][8 dwords] = 8192 B
  int tid = threadIdx.x;
  int wi = tid >> 6;
  int l = tid & 63;
  int lo = l & 31;
  int hi = l >> 5;
  int b = blockIdx.z;
  int h0 = blockIdx.y * 2;  // output rows h0, h0+1
  int wbase = blockIdx.x * 128 + wi * 32;
  int w = wbase + lo;

  const size_t img = (size_t)b * (HH * WW);
  i32x16 acc0 = {}, acc1 = {};

#if K32
  i32x4 bf[9];
  const i32x4* fp = (const i32x4*)frag;
#pragma unroll
  for (int s = 0; s < 9; ++s) bf[s] = fp[s * 64 + l];

#pragma unroll
  for (int row = 0; row < 4; ++row) {  // input rows h0-1 .. h0+2
    int yy = h0 - 1 + row;
    bool okrow = (unsigned)yy < 256u;
#pragma unroll
    for (int dx = 0; dx < 3; ++dx) {
      int xx = w + dx - 1;
      i32x4 av = {};
      if (okrow && ((unsigned)xx < 256u))
        av = *(const i32x4*)(in + ((img + (size_t)yy * WW + xx) << 5) + hi * 16);
      if (LAST) {
        if (row < 3) acc0 = __builtin_amdgcn_mfma_i32_32x32x32_i8(av, bf[row * 3 + dx], acc0, 0, 0, 0);
        if (row > 0) acc1 = __builtin_amdgcn_mfma_i32_32x32x32_i8(av, bf[(row - 1) * 3 + dx], acc1, 0, 0, 0);
      } else {
        if (row < 3) acc0 = __builtin_amdgcn_mfma_i32_32x32x32_i8(bf[row * 3 + dx], av, acc0, 0, 0, 0);
        if (row > 0) acc1 = __builtin_amdgcn_mfma_i32_32x32x32_i8(bf[(row - 1) * 3 + dx], av, acc1, 0, 0, 0);
      }
    }
  }
#else
  long bf[18];
  const long* fp = (const long*)frag;
#pragma unroll
  for (int s = 0; s < 18; ++s) bf[s] = fp[s * 64 + l];

#pragma unroll
  for (int row = 0; row < 4; ++row) {
    int yy = h0 - 1 + row;
    bool okrow = (unsigned)yy < 256u;
#pragma unroll
    for (int dx = 0; dx < 3; ++dx) {
      int xx = w + dx - 1;
#pragma unroll
      for (int s2 = 0; s2 < 2; ++s2) {
        long av = 0;
        if (okrow && ((unsigned)xx < 256u))
          av = *(const long*)(in + ((img + (size_t)yy * WW + xx) << 5) + s2 * 16 + hi * 8);
        if (LAST) {
          if (row < 3)
            acc0 = __builtin_amdgcn_mfma_i32_32x32x16_i8(av, bf[(row * 3 + dx) * 2 + s2], acc0, 0, 0, 0);
          if (row > 0)
            acc1 = __builtin_amdgcn_mfma_i32_32x32x16_i8(av, bf[((row - 1) * 3 + dx) * 2 + s2], acc1, 0, 0, 0);
        } else {
          if (row < 3)
            acc0 = __builtin_amdgcn_mfma_i32_32x32x16_i8(bf[(row * 3 + dx) * 2 + s2], av, acc0, 0, 0, 0);
          if (row > 0)
            acc1 = __builtin_amdgcn_mfma_i32_32x32x16_i8(bf[((row - 1) * 3 + dx) * 2 + s2], av, acc1, 0, 0, 0);
        }
      }
    }
  }
#endif

  if (!LAST) {
    // acc[4g+j] = (px = wbase+lo, oc = 8g+4hi+j). Stage dwords in LDS:
    // tr[row*1024 + px_rel*8 + (2g+hi)], px_rel = wi*32+lo.
    int base = (wi * 32 + lo) * 8 + hi;
#pragma unroll
    for (int g = 0; g < 4; ++g) {
      tr[base + 2 * g] =
          pack4(quant1(acc0[4 * g]), quant1(acc0[4 * g + 1]),
                quant1(acc0[4 * g + 2]), quant1(acc0[4 * g + 3]));
      tr[1024 + base + 2 * g] =
          pack4(quant1(acc1[4 * g]), quant1(acc1[4 * g + 1]),
                quant1(acc1[4 * g + 2]), quant1(acc1[4 * g + 3]));
    }
    __syncthreads();
    // coalesced readback + store: thread t -> int4 t of each row
    int4 v0 = *(const int4*)&tr[4 * tid];
    int4 v1 = *(const int4*)&tr[1024 + 4 * tid];
    int* orow = (int*)(out + ((img + (size_t)h0 * WW + (size_t)blockIdx.x * 128) << 5));
    ((int4*)orow)[tid] = v0;
    ((int4*)(orow + WW * 8))[tid] = v1;
  } else {
    int mymax = quant_max(acc1, quant_max(acc0, -128));
    mymax = max(mymax, __shfl_xor(mymax, 32));
    if (hi == 0) red[wi][lo] = mymax;
    __syncthreads();
    if (tid < 32) {
      int m = max(max(red[0][tid], red[1][tid]), max(red[2][tid], red[3][tid]));
      atomicMax(&gmax[b * 32 + tid], m);
    }
  }
}

// ================= final FC =================
__global__ void fc_kernel(const int* __restrict__ gmax, const int* __restrict__ wfcq,
                          float* __restrict__ out) {
  int b = threadIdx.x;
  if (b < BB) {
    int acc = 0;
#pragma unroll
    for (int c = 0; c < 32; ++c) acc += gmax[b * 32 + c] * wfcq[c];
    int q = (int)rintf((float)acc * 0.0078125f);  // rne(acc/128), exact
    q = min(127, max(-127, q));
    out[b] = (float)q * 0.0078125f;
  }
}

extern "C" void kernel_launch(void* const* d_in, const int* in_sizes, int n_in,
                              void* d_out, int out_size, void* d_ws, size_t ws_size,
                              hipStream_t stream) {
  const float* x   = (const float*)d_in[0];
  const float* w1  = (const float*)d_in[1];
  const float* wfc = (const float*)d_in[8];

  char* ws = (char*)d_ws;
  const size_t ACT = (size_t)BB * HH * WW * CC;  // 33,554,432 B
  signed char* A0    = (signed char*)ws;
  signed char* A1    = (signed char*)(ws + ACT);
  _Float16*    pre   = (_Float16*)A1;  // dead before layer-2 writes A1
  _Float16*    frag1 = (_Float16*)(ws + 2 * ACT);                 // 6144 B
  signed char* wfr   = (signed char*)(ws + 2 * ACT + 6144);       // 6 x 9216
  int*         wfcq  = (int*)(ws + 2 * ACT + 6144 + 6 * 9216);
  int*         gmax  = (int*)(ws + 2 * ACT + 6144 + 6 * 9216 + 128);

  prep_kernel<<<4313, 256, 0, stream>>>(
      x, w1, (const float*)d_in[2], (const float*)d_in[3], (const float*)d_in[4],
      (const float*)d_in[5], (const float*)d_in[6], (const float*)d_in[7],
      wfc, pre, frag1, wfr, wfcq, gmax);

  dim3 gridc(2, 128, 16);  // x: 128-px strip, y: 2-row pair, z: batch
  conv1_mfma_kernel<<<gridc, 256, 0, stream>>>(pre, frag1, A0);

  signed char* pin = A0;
  signed char* pout = A1;
  for (int l = 0; l < 5; ++l) {
    conv_mfma_kernel_t<false><<<gridc, 256, 0, stream>>>(pin, wfr + l * 9216, pout, nullptr);
    signed char* t = pin; pin = pout; pout = t;
  }
  conv_mfma_kernel_t<true><<<gridc, 256, 0, stream>>>(pin, wfr + 5 * 9216, nullptr, gmax);
  fc_kernel<<<1, 64, 0, stream>>>(gmax, wfcq, (float*)d_out);
}

// Round 12
// 176.280 us; speedup vs baseline: 1.3729x; 1.0426x over previous
//
#include <hip/hip_runtime.h>

#define BB 16
#define HH 256
#define WW 256

typedef int i32x4 __attribute__((ext_vector_type(4)));
typedef int i32x16 __attribute__((ext_vector_type(16)));
typedef float f32x16 __attribute__((ext_vector_type(16)));
typedef _Float16 f16x8 __attribute__((ext_vector_type(8)));

// ================= fused prep =================
__global__ __launch_bounds__(256) void prep_kernel(
    const float* __restrict__ x, const float* __restrict__ w1,
    const float* __restrict__ w2, const float* __restrict__ w3,
    const float* __restrict__ w4, const float* __restrict__ w5,
    const float* __restrict__ w6, const float* __restrict__ w7,
    const float* __restrict__ wfc,
    _Float16* __restrict__ pre, _Float16* __restrict__ frag1,
    signed char* __restrict__ wfr, int* __restrict__ wfcq,
    int* __restrict__ gmax) {
  int bid = blockIdx.x, tid = threadIdx.x;
  if (bid < 4096) {
    int px = bid * 256 + tid;  // 1,048,576 pixels
    int b = px >> 16, rem = px & 65535;
    const float* xp = x + (size_t)b * 4 * 65536 + rem;
    f16x8 o;
#pragma unroll
    for (int ic = 0; ic < 4; ++ic) {
      float v = xp[ic * 65536];
      _Float16 hf = (_Float16)v;
      float r = v - (float)hf;
      o[ic * 2] = hf;
      o[ic * 2 + 1] = (_Float16)r;
    }
    *(f16x8*)(pre + (size_t)px * 8) = o;
  } else if (bid < 4312) {
    int i = (bid - 4096) * 256 + tid;  // 6 x 9216
    int layer = i / 9216, within = i - layer * 9216;
    const float* w = layer == 0 ? w2 : layer == 1 ? w3 : layer == 2 ? w4
                   : layer == 3 ? w5 : layer == 4 ? w6 : w7;
    int t = within >> 10;
    int l = (within >> 4) & 63;
    int j = within & 15;
    int ic = (l >> 5) * 16 + j;
    int oc = l & 31;
    int q = (int)rintf(w[oc * 288 + ic * 9 + t] * 128.0f);
    q = min(127, max(-127, q));
    wfr[(size_t)layer * 9216 + within] = (signed char)q;
  } else {
    // conv1 f16 B-frags
    for (int p = tid; p < 384; p += 256) {
      int s = p >> 6, l = p & 63;
      int dr = s >> 1, pp = s & 1;
      int oc = l & 31, half = l >> 5;
      int dx = pp * 2 + half;
#pragma unroll
      for (int j = 0; j < 8; ++j) {
        int ic = j >> 1;
        _Float16 v = (_Float16)0.f;
        if (!(pp == 1 && half == 1)) {
          int q = (int)rintf(w1[oc * 36 + ic * 9 + dr * 3 + dx] * 128.0f);
          q = min(127, max(-127, q));
          v = (_Float16)((float)q * 0.0078125f);  // exact in fp16
        }
        frag1[s * 512 + l * 8 + j] = v;
      }
    }
    if (tid < 32) {
      int q = (int)rintf(wfc[tid] * 128.0f);
      q = min(127, max(-127, q));
      wfcq[tid] = q;
    }
    for (int i2 = tid; i2 < 512; i2 += 256) gmax[i2] = -128;
  }
}

// ================= conv1: f16 hi/lo implicit-GEMM MFMA =================
__global__ __launch_bounds__(256) void conv1_mfma_kernel(
    const _Float16* __restrict__ pre, const _Float16* __restrict__ frag1,
    signed char* __restrict__ out) {
  int tid = threadIdx.x;
  int wi = tid >> 6;
  int l = tid & 63;
  int lo = l & 31;
  int hi = l >> 5;
  int b = blockIdx.z;
  int h0 = blockIdx.y * 2;
  int wbase = blockIdx.x * 128 + wi * 32;
  int w = wbase + lo;

  const f16x8* fp = (const f16x8*)frag1;
  f16x8 bf[6];
#pragma unroll
  for (int s = 0; s < 6; ++s) bf[s] = fp[s * 64 + l];

  f32x16 acc0 = {}, acc1 = {};
  const size_t img = (size_t)b * (HH * WW);

#pragma unroll
  for (int r = 0; r < 4; ++r) {  // input rows h0-1 .. h0+2
    int yy = h0 - 1 + r;
    bool okr = (unsigned)yy < 256u;
#pragma unroll
    for (int p = 0; p < 2; ++p) {
      int xx = w + p * 2 + hi - 1;  // dx = 2p + half
      f16x8 av = {};
      if (okr && !(p == 1 && hi == 1) && ((unsigned)xx < 256u))
        av = *(const f16x8*)(pre + ((img + (size_t)yy * WW + xx) << 3));
      if (r < 3) acc0 = __builtin_amdgcn_mfma_f32_32x32x16_f16(av, bf[r * 2 + p], acc0, 0, 0, 0);
      if (r > 0) acc1 = __builtin_amdgcn_mfma_f32_32x32x16_f16(av, bf[(r - 1) * 2 + p], acc1, 0, 0, 0);
    }
  }

  signed char* op = out + ((img + (size_t)h0 * WW + wbase) << 5) + lo;
#pragma unroll
  for (int r = 0; r < 16; ++r) {
    int row = (r & 3) + 8 * (r >> 2) + 4 * hi;
    int q0 = (int)rintf(acc0[r] * 128.0f);
    q0 = min(127, max(-127, q0));
    op[row * 32] = (signed char)q0;
    int q1 = (int)rintf(acc1[r] * 128.0f);
    q1 = min(127, max(-127, q1));
    op[WW * 32 + row * 32] = (signed char)q1;
  }
}

// ================= mid/last convs: sliding-window =================
__device__ __forceinline__ int quant1(int a) {
  int q = (int)rintf((float)a * 0.0078125f);  // rne(acc/128), exact in fp32
  return min(127, max(-127, q));
}

__device__ __forceinline__ int quant_max(const i32x16& acc, int mymax) {
#pragma unroll
  for (int r = 0; r < 16; ++r) mymax = max(mymax, quant1(acc[r]));
  return mymax;
}

__device__ __forceinline__ int pack4(int q0, int q1, int q2, int q3) {
  return (q0 & 255) | ((q1 & 255) << 8) | ((q2 & 255) << 16) | ((q3 & 255) << 24);
}

// Each block: 128-px strip x 8 output rows x 32 oc. Rows roll through regs
// (6 new loads per 2-row pair, prefetched one pair ahead); weight frags in
// LDS (asm-laundered index stops LICM from hoisting them into 36 VGPRs).
// Mid: swapped operands (A=weights, lane owns pixel) + LDS-staged coalesced
// stores (bit-exact since round 7/9). LAST: A=activations, per-oc max only.
template <bool LAST>
__global__ __launch_bounds__(256) void conv_slide_kernel_t(
    const signed char* __restrict__ in, const signed char* __restrict__ frag,
    signed char* __restrict__ out, int* __restrict__ gmax) {
  __shared__ int lbf[2304];  // 9216 B weight frags
  __shared__ int tr[2048];   // 8 KB epilogue staging
  __shared__ int red[4][32];
  int tid = threadIdx.x;
  int wi = tid >> 6;
  int l = tid & 63;
  int lo = l & 31;
  int hi = l >> 5;

  const int* f32p = (const int*)frag;
  for (int i = tid; i < 2304; i += 256) lbf[i] = f32p[i];
  __syncthreads();

  int b = blockIdx.z;
  int hs = blockIdx.y * 8;  // output rows hs .. hs+7
  int wbase = blockIdx.x * 128 + wi * 32;
  int w = wbase + lo;
  const size_t img = (size_t)b * (HH * WW);

  auto ldrow = [&](int yy, int dx) -> i32x4 {
    i32x4 r = {};
    int xx = w + dx - 1;
    if (((unsigned)yy < 256u) && ((unsigned)xx < 256u))
      r = *(const i32x4*)(in + ((img + (size_t)yy * WW + xx) << 5) + hi * 16);
    return r;
  };

  // rows for current pair: ra=h0-1, rb=h0, rc=h0+1, rd=h0+2
  i32x4 ra[3], rb[3], rc[3], rd[3];
#pragma unroll
  for (int dx = 0; dx < 3; ++dx) {
    ra[dx] = ldrow(hs - 1, dx);
    rb[dx] = ldrow(hs, dx);
    rc[dx] = ldrow(hs + 1, dx);
    rd[dx] = ldrow(hs + 2, dx);
  }

  int mymax = -128;
#pragma unroll 1
  for (int p = 0; p < 4; ++p) {
    int h0 = hs + 2 * p;
    // prefetch next pair's two new rows (latency hides under MFMAs+epilogue)
    i32x4 re[3] = {}, rf[3] = {};
    if (p < 3) {
#pragma unroll
      for (int dx = 0; dx < 3; ++dx) {
        re[dx] = ldrow(h0 + 3, dx);
        rf[dx] = ldrow(h0 + 4, dx);
      }
    }

    int pz = 0;
    asm volatile("" : "+v"(pz));  // opaque 0: force per-pair LDS re-read of bf

    i32x16 acc0 = {}, acc1 = {};
#pragma unroll
    for (int t = 0; t < 9; ++t) {
      int dy = t / 3, dx = t % 3;
      i32x4 bfv = *(const i32x4*)&lbf[(t * 64 + l) * 4 + pz];
      i32x4 a0 = (dy == 0) ? ra[dx] : (dy == 1) ? rb[dx] : rc[dx];
      i32x4 a1 = (dy == 0) ? rb[dx] : (dy == 1) ? rc[dx] : rd[dx];
      if (LAST) {
        acc0 = __builtin_amdgcn_mfma_i32_32x32x32_i8(a0, bfv, acc0, 0, 0, 0);
        acc1 = __builtin_amdgcn_mfma_i32_32x32x32_i8(a1, bfv, acc1, 0, 0, 0);
      } else {
        acc0 = __builtin_amdgcn_mfma_i32_32x32x32_i8(bfv, a0, acc0, 0, 0, 0);
        acc1 = __builtin_amdgcn_mfma_i32_32x32x32_i8(bfv, a1, acc1, 0, 0, 0);
      }
    }

    if (!LAST) {
      // lane owns px = wbase+lo; oc = (r&3)+8*(r>>2)+4*hi.
      int base = (wi * 32 + lo) * 8 + hi;
#pragma unroll
      for (int g = 0; g < 4; ++g) {
        tr[base + 2 * g] =
            pack4(quant1(acc0[4 * g]), quant1(acc0[4 * g + 1]),
                  quant1(acc0[4 * g + 2]), quant1(acc0[4 * g + 3]));
        tr[1024 + base + 2 * g] =
            pack4(quant1(acc1[4 * g]), quant1(acc1[4 * g + 1]),
                  quant1(acc1[4 * g + 2]), quant1(acc1[4 * g + 3]));
      }
      __syncthreads();
      int4 v0 = *(const int4*)&tr[4 * tid];
      int4 v1 = *(const int4*)&tr[1024 + 4 * tid];
      int* orow = (int*)(out + ((img + (size_t)h0 * WW + (size_t)blockIdx.x * 128) << 5));
      ((int4*)orow)[tid] = v0;
      ((int4*)(orow + WW * 8))[tid] = v1;
      __syncthreads();  // protect tr reuse next pair
    } else {
      mymax = quant_max(acc1, quant_max(acc0, mymax));
    }

    // roll rows down by 2
#pragma unroll
    for (int dx = 0; dx < 3; ++dx) {
      ra[dx] = rc[dx];
      rb[dx] = rd[dx];
      rc[dx] = re[dx];
      rd[dx] = rf[dx];
    }
  }

  if (LAST) {
    mymax = max(mymax, __shfl_xor(mymax, 32));
    if (hi == 0) red[wi][lo] = mymax;
    __syncthreads();
    if (tid < 32) {
      int m = max(max(red[0][tid], red[1][tid]), max(red[2][tid], red[3][tid]));
      atomicMax(&gmax[b * 32 + tid], m);
    }
  }
}

// ================= final FC =================
__global__ void fc_kernel(const int* __restrict__ gmax, const int* __restrict__ wfcq,
                          float* __restrict__ out) {
  int b = threadIdx.x;
  if (b < BB) {
    int acc = 0;
#pragma unroll
    for (int c = 0; c < 32; ++c) acc += gmax[b * 32 + c] * wfcq[c];
    int q = (int)rintf((float)acc * 0.0078125f);  // rne(acc/128), exact
    q = min(127, max(-127, q));
    out[b] = (float)q * 0.0078125f;
  }
}

extern "C" void kernel_launch(void* const* d_in, const int* in_sizes, int n_in,
                              void* d_out, int out_size, void* d_ws, size_t ws_size,
                              hipStream_t stream) {
  const float* x   = (const float*)d_in[0];
  const float* w1  = (const float*)d_in[1];
  const float* wfc = (const float*)d_in[8];

  char* ws = (char*)d_ws;
  const size_t ACTB = (size_t)BB * HH * WW * 32;  // 33,554,432 B
  signed char* A0    = (signed char*)ws;
  signed char* A1    = (signed char*)(ws + ACTB);
  _Float16*    pre   = (_Float16*)A1;  // dead before layer-2 writes A1
  _Float16*    frag1 = (_Float16*)(ws + 2 * ACTB);                 // 6144 B
  signed char* wfr   = (signed char*)(ws + 2 * ACTB + 6144);       // 6 x 9216
  int*         wfcq  = (int*)(ws + 2 * ACTB + 6144 + 6 * 9216);
  int*         gmax  = (int*)(ws + 2 * ACTB + 6144 + 6 * 9216 + 128);

  prep_kernel<<<4313, 256, 0, stream>>>(
      x, w1, (const float*)d_in[2], (const float*)d_in[3], (const float*)d_in[4],
      (const float*)d_in[5], (const float*)d_in[6], (const float*)d_in[7],
      wfc, pre, frag1, wfr, wfcq, gmax);

  dim3 gridc1(2, 128, 16);  // conv1: 2-row pairs
  conv1_mfma_kernel<<<gridc1, 256, 0, stream>>>(pre, frag1, A0);

  dim3 grids(2, 32, 16);    // sliding mids: 8-row chunks
  signed char* pin = A0;
  signed char* pout = A1;
  for (int l = 0; l < 5; ++l) {
    conv_slide_kernel_t<false><<<grids, 256, 0, stream>>>(pin, wfr + l * 9216, pout, nullptr);
    signed char* t = pin; pin = pout; pout = t;
  }
  conv_slide_kernel_t<true><<<grids, 256, 0, stream>>>(pin, wfr + 5 * 9216, nullptr, gmax);
  fc_kernel<<<1, 64, 0, stream>>>(gmax, wfcq, (float*)d_out);
}

// Round 13
// 173.346 us; speedup vs baseline: 1.3961x; 1.0169x over previous
//
#include <hip/hip_runtime.h>

#define BB 16
#define HH 256
#define WW 256

typedef int i32x4 __attribute__((ext_vector_type(4)));
typedef int i32x16 __attribute__((ext_vector_type(16)));
typedef float f32x16 __attribute__((ext_vector_type(16)));
typedef _Float16 f16x8 __attribute__((ext_vector_type(8)));

// ================= fused prep =================
__global__ __launch_bounds__(256) void prep_kernel(
    const float* __restrict__ x, const float* __restrict__ w1,
    const float* __restrict__ w2, const float* __restrict__ w3,
    const float* __restrict__ w4, const float* __restrict__ w5,
    const float* __restrict__ w6, const float* __restrict__ w7,
    const float* __restrict__ wfc,
    _Float16* __restrict__ pre, _Float16* __restrict__ frag1,
    signed char* __restrict__ wfr, int* __restrict__ wfcq,
    int* __restrict__ gmax) {
  int bid = blockIdx.x, tid = threadIdx.x;
  if (bid < 4096) {
    int px = bid * 256 + tid;  // 1,048,576 pixels
    int b = px >> 16, rem = px & 65535;
    const float* xp = x + (size_t)b * 4 * 65536 + rem;
    f16x8 o;
#pragma unroll
    for (int ic = 0; ic < 4; ++ic) {
      float v = xp[ic * 65536];
      _Float16 hf = (_Float16)v;
      float r = v - (float)hf;
      o[ic * 2] = hf;
      o[ic * 2 + 1] = (_Float16)r;
    }
    *(f16x8*)(pre + (size_t)px * 8) = o;
  } else if (bid < 4312) {
    int i = (bid - 4096) * 256 + tid;  // 6 x 9216
    int layer = i / 9216, within = i - layer * 9216;
    const float* w = layer == 0 ? w2 : layer == 1 ? w3 : layer == 2 ? w4
                   : layer == 3 ? w5 : layer == 4 ? w6 : w7;
    int t = within >> 10;
    int l = (within >> 4) & 63;
    int j = within & 15;
    int ic = (l >> 5) * 16 + j;
    int oc = l & 31;
    int q = (int)rintf(w[oc * 288 + ic * 9 + t] * 128.0f);
    q = min(127, max(-127, q));
    wfr[(size_t)layer * 9216 + within] = (signed char)q;
  } else {
    // conv1 f16 B-frags
    for (int p = tid; p < 384; p += 256) {
      int s = p >> 6, l = p & 63;
      int dr = s >> 1, pp = s & 1;
      int oc = l & 31, half = l >> 5;
      int dx = pp * 2 + half;
#pragma unroll
      for (int j = 0; j < 8; ++j) {
        int ic = j >> 1;
        _Float16 v = (_Float16)0.f;
        if (!(pp == 1 && half == 1)) {
          int q = (int)rintf(w1[oc * 36 + ic * 9 + dr * 3 + dx] * 128.0f);
          q = min(127, max(-127, q));
          v = (_Float16)((float)q * 0.0078125f);  // exact in fp16
        }
        frag1[s * 512 + l * 8 + j] = v;
      }
    }
    if (tid < 32) {
      int q = (int)rintf(wfc[tid] * 128.0f);
      q = min(127, max(-127, q));
      wfcq[tid] = q;
    }
    for (int i2 = tid; i2 < 512; i2 += 256) gmax[i2] = -128;
  }
}

// ================= conv1: f16 hi/lo implicit-GEMM MFMA =================
__global__ __launch_bounds__(256) void conv1_mfma_kernel(
    const _Float16* __restrict__ pre, const _Float16* __restrict__ frag1,
    signed char* __restrict__ out) {
  int tid = threadIdx.x;
  int wi = tid >> 6;
  int l = tid & 63;
  int lo = l & 31;
  int hi = l >> 5;
  int b = blockIdx.z;
  int h0 = blockIdx.y * 2;
  int wbase = blockIdx.x * 128 + wi * 32;
  int w = wbase + lo;

  const f16x8* fp = (const f16x8*)frag1;
  f16x8 bf[6];
#pragma unroll
  for (int s = 0; s < 6; ++s) bf[s] = fp[s * 64 + l];

  f32x16 acc0 = {}, acc1 = {};
  const size_t img = (size_t)b * (HH * WW);

#pragma unroll
  for (int r = 0; r < 4; ++r) {  // input rows h0-1 .. h0+2
    int yy = h0 - 1 + r;
    bool okr = (unsigned)yy < 256u;
#pragma unroll
    for (int p = 0; p < 2; ++p) {
      int xx = w + p * 2 + hi - 1;  // dx = 2p + half
      f16x8 av = {};
      if (okr && !(p == 1 && hi == 1) && ((unsigned)xx < 256u))
        av = *(const f16x8*)(pre + ((img + (size_t)yy * WW + xx) << 3));
      if (r < 3) acc0 = __builtin_amdgcn_mfma_f32_32x32x16_f16(av, bf[r * 2 + p], acc0, 0, 0, 0);
      if (r > 0) acc1 = __builtin_amdgcn_mfma_f32_32x32x16_f16(av, bf[(r - 1) * 2 + p], acc1, 0, 0, 0);
    }
  }

  signed char* op = out + ((img + (size_t)h0 * WW + wbase) << 5) + lo;
#pragma unroll
  for (int r = 0; r < 16; ++r) {
    int row = (r & 3) + 8 * (r >> 2) + 4 * hi;
    int q0 = (int)rintf(acc0[r] * 128.0f);
    q0 = min(127, max(-127, q0));
    op[row * 32] = (signed char)q0;
    int q1 = (int)rintf(acc1[r] * 128.0f);
    q1 = min(127, max(-127, q1));
    op[WW * 32 + row * 32] = (signed char)q1;
  }
}

// ================= fused mid pairs =================
__device__ __forceinline__ int quant1(int a) {
  int q = (int)rintf((float)a * 0.0078125f);  // rne(acc/128), exact in fp32
  return min(127, max(-127, q));
}

__device__ __forceinline__ int quant_max(const i32x16& acc, int mymax) {
#pragma unroll
  for (int r = 0; r < 16; ++r) mymax = max(mymax, quant1(acc[r]));
  return mymax;
}

__device__ __forceinline__ int pack4(int q0, int q1, int q2, int q3) {
  return (q0 & 255) | ((q1 & 255) << 8) | ((q2 & 255) << 16) | ((q3 & 255) << 24);
}

// Two conv layers fused. Block = 512 thr (8 waves x 32-px strips, full width),
// 4 output rows of layer B. Phase 1: layer A rows hs-1..hs+4 (6 rows) -> LDS
// (XOR-swizzled int8 NHWC). Phase 2: layer B rows hs..hs+3 from LDS.
// Swizzle: channel-dword d of pixel px stored at slot d ^ (((px>>2)&1)<<2)
// -> phase-2 b128 tap reads spread over all 8 bank-groups (~conflict-free).
// MODE 0: layer B stores to global (swapped orientation, lane owns px).
// MODE 1: layer B is the net's last conv -> per-oc global max only.
template <int MODE>
__global__ __launch_bounds__(512, 4) void conv_fused_kernel(
    const signed char* __restrict__ in, const signed char* __restrict__ fragA,
    const signed char* __restrict__ fragB, signed char* __restrict__ out,
    int* __restrict__ gmax) {
  __shared__ int Lint[6 * 256 * 8];  // 49152 B
  __shared__ int lbf[2304];          // 9216 B, holds A-frags then B-frags
  __shared__ int red[8][32];

  int tid = threadIdx.x;
  int wi = tid >> 6;
  int l = tid & 63;
  int lo = l & 31;
  int hi = l >> 5;
  int b = blockIdx.y;
  int hs = blockIdx.x * 4;  // layer-B output rows hs..hs+3
  int w = wi * 32 + lo;     // this lane's pixel column
  const size_t img = (size_t)b * (HH * WW);

  const int* fA32 = (const int*)fragA;
  for (int i = tid; i < 2304; i += 512) lbf[i] = fA32[i];
  __syncthreads();

  auto ldrow = [&](int yy, int dx) -> i32x4 {
    i32x4 r = {};
    int xx = w + dx - 1;
    if (((unsigned)yy < 256u) && ((unsigned)xx < 256u))
      r = *(const i32x4*)(in + ((img + (size_t)yy * WW + xx) << 5) + hi * 16);
    return r;
  };

  int swz = ((w >> 2) & 1) << 2;

  // ---- phase 1: layer A, rows hs-1 .. hs+4 (rrel 0..5) ----
  i32x4 ra[3], rb[3], rc[3], rd[3];
#pragma unroll
  for (int dx = 0; dx < 3; ++dx) {
    ra[dx] = ldrow(hs - 2, dx);
    rb[dx] = ldrow(hs - 1, dx);
    rc[dx] = ldrow(hs, dx);
    rd[dx] = ldrow(hs + 1, dx);
  }

#pragma unroll 1
  for (int p = 0; p < 3; ++p) {
    int pz = 0;
    asm volatile("" : "+v"(pz));  // force per-pair LDS weight re-read
    i32x16 acc0 = {}, acc1 = {};
#pragma unroll
    for (int t = 0; t < 9; ++t) {
      int dy = t / 3, dx = t % 3;
      i32x4 bfv = *(const i32x4*)&lbf[(t * 64 + l) * 4 + pz];
      i32x4 a0 = (dy == 0) ? ra[dx] : (dy == 1) ? rb[dx] : rc[dx];
      i32x4 a1 = (dy == 0) ? rb[dx] : (dy == 1) ? rc[dx] : rd[dx];
      acc0 = __builtin_amdgcn_mfma_i32_32x32x32_i8(bfv, a0, acc0, 0, 0, 0);
      acc1 = __builtin_amdgcn_mfma_i32_32x32x32_i8(bfv, a1, acc1, 0, 0, 0);
    }
    // write rows rrel 2p, 2p+1 to LDS (lane owns px=w; dwords 2g+hi)
    int base0 = ((2 * p) * 256 + w) * 8;
#pragma unroll
    for (int g = 0; g < 4; ++g) {
      int d = 2 * g + hi;
      int v0 = pack4(quant1(acc0[4 * g]), quant1(acc0[4 * g + 1]),
                     quant1(acc0[4 * g + 2]), quant1(acc0[4 * g + 3]));
      int v1 = pack4(quant1(acc1[4 * g]), quant1(acc1[4 * g + 1]),
                     quant1(acc1[4 * g + 2]), quant1(acc1[4 * g + 3]));
      Lint[base0 + (d ^ swz)] = v0;
      Lint[base0 + 2048 + (d ^ swz)] = v1;
    }
    if (p < 2) {
#pragma unroll
      for (int dx = 0; dx < 3; ++dx) {
        ra[dx] = rc[dx];
        rb[dx] = rd[dx];
        rc[dx] = ldrow(hs + 2 + 2 * p, dx);
        rd[dx] = ldrow(hs + 3 + 2 * p, dx);
      }
    }
  }

  __syncthreads();
  const int* fB32 = (const int*)fragB;
  for (int i = tid; i < 2304; i += 512) lbf[i] = fB32[i];
  __syncthreads();

  // ---- phase 2: layer B, rows hs..hs+3 from LDS ----
  int mymax = -128;
#pragma unroll 1
  for (int p = 0; p < 2; ++p) {
    i32x4 tp[4][3];
#pragma unroll
    for (int rr = 0; rr < 4; ++rr) {
      int rrel = 2 * p + rr;
      int aro = hs - 1 + rrel;  // absolute layer-A row
#pragma unroll
      for (int dx = 0; dx < 3; ++dx) {
        int px = w + dx - 1;
        i32x4 v = {};
        if (((unsigned)aro < 256u) && ((unsigned)px < 256u)) {
          int idx = (rrel * 256 + px) * 8 + 4 * (hi ^ ((px >> 2) & 1));
          v = *(const i32x4*)&Lint[idx];
        }
        tp[rr][dx] = v;
      }
    }
    int pz = 0;
    asm volatile("" : "+v"(pz));
    i32x16 acc0 = {}, acc1 = {};
#pragma unroll
    for (int t = 0; t < 9; ++t) {
      int dy = t / 3, dx = t % 3;
      i32x4 bfv = *(const i32x4*)&lbf[(t * 64 + l) * 4 + pz];
      if (MODE == 1) {
        acc0 = __builtin_amdgcn_mfma_i32_32x32x32_i8(tp[dy][dx], bfv, acc0, 0, 0, 0);
        acc1 = __builtin_amdgcn_mfma_i32_32x32x32_i8(tp[dy + 1][dx], bfv, acc1, 0, 0, 0);
      } else {
        acc0 = __builtin_amdgcn_mfma_i32_32x32x32_i8(bfv, tp[dy][dx], acc0, 0, 0, 0);
        acc1 = __builtin_amdgcn_mfma_i32_32x32x32_i8(bfv, tp[dy + 1][dx], acc1, 0, 0, 0);
      }
    }
    if (MODE == 0) {
      // lane owns px=w; dword d=2g+hi of rows hs+2p, hs+2p+1
      int* o32 = (int*)out;
      size_t base = (img + (size_t)(hs + 2 * p) * WW + w) * 8;
#pragma unroll
      for (int g = 0; g < 4; ++g) {
        int v0 = pack4(quant1(acc0[4 * g]), quant1(acc0[4 * g + 1]),
                       quant1(acc0[4 * g + 2]), quant1(acc0[4 * g + 3]));
        int v1 = pack4(quant1(acc1[4 * g]), quant1(acc1[4 * g + 1]),
                       quant1(acc1[4 * g + 2]), quant1(acc1[4 * g + 3]));
        o32[base + 2 * g + hi] = v0;
        o32[base + 2048 + 2 * g + hi] = v1;
      }
    } else {
      mymax = quant_max(acc1, quant_max(acc0, mymax));
    }
  }

  if (MODE == 1) {
    mymax = max(mymax, __shfl_xor(mymax, 32));  // lanes lo & lo+32: same oc
    if (hi == 0) red[wi][lo] = mymax;
    __syncthreads();
    if (tid < 32) {
      int m = -128;
#pragma unroll
      for (int r = 0; r < 8; ++r) m = max(m, red[r][tid]);
      atomicMax(&gmax[b * 32 + tid], m);
    }
  }
}

// ================= final FC =================
__global__ void fc_kernel(const int* __restrict__ gmax, const int* __restrict__ wfcq,
                          float* __restrict__ out) {
  int b = threadIdx.x;
  if (b < BB) {
    int acc = 0;
#pragma unroll
    for (int c = 0; c < 32; ++c) acc += gmax[b * 32 + c] * wfcq[c];
    int q = (int)rintf((float)acc * 0.0078125f);  // rne(acc/128), exact
    q = min(127, max(-127, q));
    out[b] = (float)q * 0.0078125f;
  }
}

extern "C" void kernel_launch(void* const* d_in, const int* in_sizes, int n_in,
                              void* d_out, int out_size, void* d_ws, size_t ws_size,
                              hipStream_t stream) {
  const float* x   = (const float*)d_in[0];
  const float* w1  = (const float*)d_in[1];
  const float* wfc = (const float*)d_in[8];

  char* ws = (char*)d_ws;
  const size_t ACTB = (size_t)BB * HH * WW * 32;  // 33,554,432 B
  signed char* A0    = (signed char*)ws;
  signed char* A1    = (signed char*)(ws + ACTB);
  _Float16*    pre   = (_Float16*)A1;  // dead before F0 writes A1
  _Float16*    frag1 = (_Float16*)(ws + 2 * ACTB);                 // 6144 B
  signed char* wfr   = (signed char*)(ws + 2 * ACTB + 6144);       // 6 x 9216
  int*         wfcq  = (int*)(ws + 2 * ACTB + 6144 + 6 * 9216);
  int*         gmax  = (int*)(ws + 2 * ACTB + 6144 + 6 * 9216 + 128);

  prep_kernel<<<4313, 256, 0, stream>>>(
      x, w1, (const float*)d_in[2], (const float*)d_in[3], (const float*)d_in[4],
      (const float*)d_in[5], (const float*)d_in[6], (const float*)d_in[7],
      wfc, pre, frag1, wfr, wfcq, gmax);

  dim3 gridc1(2, 128, 16);  // conv1: 2-row pairs
  conv1_mfma_kernel<<<gridc1, 256, 0, stream>>>(pre, frag1, A0);

  dim3 gf(64, 16);  // fused pairs: 4-row chunks, full width
  conv_fused_kernel<0><<<gf, 512, 0, stream>>>(A0, wfr + 0 * 9216, wfr + 1 * 9216, A1, nullptr);
  conv_fused_kernel<0><<<gf, 512, 0, stream>>>(A1, wfr + 2 * 9216, wfr + 3 * 9216, A0, nullptr);
  conv_fused_kernel<1><<<gf, 512, 0, stream>>>(A0, wfr + 4 * 9216, wfr + 5 * 9216, nullptr, gmax);
  fc_kernel<<<1, 64, 0, stream>>>(gmax, wfcq, (float*)d_out);
}

// Round 15
// 168.482 us; speedup vs baseline: 1.4364x; 1.0289x over previous
//
#include <hip/hip_runtime.h>

#define BB 16
#define HH 256
#define WW 256

typedef int i32x4 __attribute__((ext_vector_type(4)));
typedef int i32x16 __attribute__((ext_vector_type(16)));
typedef float f32x16 __attribute__((ext_vector_type(16)));
typedef _Float16 f16x8 __attribute__((ext_vector_type(8)));

// ================= fused prep =================
__global__ __launch_bounds__(256) void prep_kernel(
    const float* __restrict__ x, const float* __restrict__ w1,
    const float* __restrict__ w2, const float* __restrict__ w3,
    const float* __restrict__ w4, const float* __restrict__ w5,
    const float* __restrict__ w6, const float* __restrict__ w7,
    const float* __restrict__ wfc,
    _Float16* __restrict__ pre, _Float16* __restrict__ frag1,
    signed char* __restrict__ wfr, int* __restrict__ wfcq,
    int* __restrict__ gmax) {
  int bid = blockIdx.x, tid = threadIdx.x;
  if (bid < 4096) {
    int px = bid * 256 + tid;  // 1,048,576 pixels
    int b = px >> 16, rem = px & 65535;
    const float* xp = x + (size_t)b * 4 * 65536 + rem;
    f16x8 o;
#pragma unroll
    for (int ic = 0; ic < 4; ++ic) {
      float v = xp[ic * 65536];
      _Float16 hf = (_Float16)v;
      float r = v - (float)hf;
      o[ic * 2] = hf;
      o[ic * 2 + 1] = (_Float16)r;
    }
    *(f16x8*)(pre + (size_t)px * 8) = o;
  } else if (bid < 4312) {
    int i = (bid - 4096) * 256 + tid;  // 6 x 9216
    int layer = i / 9216, within = i - layer * 9216;
    const float* w = layer == 0 ? w2 : layer == 1 ? w3 : layer == 2 ? w4
                   : layer == 3 ? w5 : layer == 4 ? w6 : w7;
    int t = within >> 10;
    int l = (within >> 4) & 63;
    int j = within & 15;
    int ic = (l >> 5) * 16 + j;
    int oc = l & 31;
    int q = (int)rintf(w[oc * 288 + ic * 9 + t] * 128.0f);
    q = min(127, max(-127, q));
    wfr[(size_t)layer * 9216 + within] = (signed char)q;
  } else {
    // conv1 f16 B-frags
    for (int p = tid; p < 384; p += 256) {
      int s = p >> 6, l = p & 63;
      int dr = s >> 1, pp = s & 1;
      int oc = l & 31, half = l >> 5;
      int dx = pp * 2 + half;
#pragma unroll
      for (int j = 0; j < 8; ++j) {
        int ic = j >> 1;
        _Float16 v = (_Float16)0.f;
        if (!(pp == 1 && half == 1)) {
          int q = (int)rintf(w1[oc * 36 + ic * 9 + dr * 3 + dx] * 128.0f);
          q = min(127, max(-127, q));
          v = (_Float16)((float)q * 0.0078125f);  // exact in fp16
        }
        frag1[s * 512 + l * 8 + j] = v;
      }
    }
    if (tid < 32) {
      int q = (int)rintf(wfc[tid] * 128.0f);
      q = min(127, max(-127, q));
      wfcq[tid] = q;
    }
    for (int i2 = tid; i2 < 512; i2 += 256) gmax[i2] = -128;
  }
}

// ================= conv1: f16 hi/lo implicit-GEMM MFMA =================
__global__ __launch_bounds__(256) void conv1_mfma_kernel(
    const _Float16* __restrict__ pre, const _Float16* __restrict__ frag1,
    signed char* __restrict__ out) {
  int tid = threadIdx.x;
  int wi = tid >> 6;
  int l = tid & 63;
  int lo = l & 31;
  int hi = l >> 5;
  int b = blockIdx.z;
  int h0 = blockIdx.y * 2;
  int wbase = blockIdx.x * 128 + wi * 32;
  int w = wbase + lo;

  const f16x8* fp = (const f16x8*)frag1;
  f16x8 bf[6];
#pragma unroll
  for (int s = 0; s < 6; ++s) bf[s] = fp[s * 64 + l];

  f32x16 acc0 = {}, acc1 = {};
  const size_t img = (size_t)b * (HH * WW);

#pragma unroll
  for (int r = 0; r < 4; ++r) {  // input rows h0-1 .. h0+2
    int yy = h0 - 1 + r;
    bool okr = (unsigned)yy < 256u;
#pragma unroll
    for (int p = 0; p < 2; ++p) {
      int xx = w + p * 2 + hi - 1;  // dx = 2p + half
      f16x8 av = {};
      if (okr && !(p == 1 && hi == 1) && ((unsigned)xx < 256u))
        av = *(const f16x8*)(pre + ((img + (size_t)yy * WW + xx) << 3));
      if (r < 3) acc0 = __builtin_amdgcn_mfma_f32_32x32x16_f16(av, bf[r * 2 + p], acc0, 0, 0, 0);
      if (r > 0) acc1 = __builtin_amdgcn_mfma_f32_32x32x16_f16(av, bf[(r - 1) * 2 + p], acc1, 0, 0, 0);
    }
  }

  signed char* op = out + ((img + (size_t)h0 * WW + wbase) << 5) + lo;
#pragma unroll
  for (int r = 0; r < 16; ++r) {
    int row = (r & 3) + 8 * (r >> 2) + 4 * hi;
    int q0 = (int)rintf(acc0[r] * 128.0f);
    q0 = min(127, max(-127, q0));
    op[row * 32] = (signed char)q0;
    int q1 = (int)rintf(acc1[r] * 128.0f);
    q1 = min(127, max(-127, q1));
    op[WW * 32 + row * 32] = (signed char)q1;
  }
}

// ================= fused mid pairs =================
__device__ __forceinline__ int quant1(int a) {
  int q = (int)rintf((float)a * 0.0078125f);  // rne(acc/128), exact in fp32
  return min(127, max(-127, q));
}

__device__ __forceinline__ int quant_max(const i32x16& acc, int mymax) {
#pragma unroll
  for (int r = 0; r < 16; ++r) mymax = max(mymax, quant1(acc[r]));
  return mymax;
}

__device__ __forceinline__ int pack4(int q0, int q1, int q2, int q3) {
  return (q0 & 255) | ((q1 & 255) << 8) | ((q2 & 255) << 16) | ((q3 & 255) << 24);
}

// Two conv layers fused. Block = 512 thr (8 waves, each wave = 32-px strip
// x 2 channel-halves), layer-B output rows hs..hs+3.
// LDS layout for the intermediate: [rrel 0..5][half 0..1][px 0..255] in 16B
// units -> phase-2 taps are ds_read_b128 with consecutive lanes reading
// consecutive 16B chunks (streaming, conflict-free). Phase-1 writes are b32
// at 4-dword stride (4-way, cheap, 24/thread).
// MODE 0: layer B stores to global (swapped orientation, lane owns px).
// MODE 1: layer B is the net's last conv -> per-oc global max only.
template <int MODE>
__global__ __launch_bounds__(512, 4) void conv_fused_kernel(
    const signed char* __restrict__ in, const signed char* __restrict__ fragA,
    const signed char* __restrict__ fragB, signed char* __restrict__ out,
    int* __restrict__ gmax) {
  __shared__ int Lint[6 * 2 * 256 * 4];  // 49152 B
  __shared__ int lbf[2304];              // 9216 B, A-frags then B-frags
  __shared__ int red[8][32];

  int tid = threadIdx.x;
  int wi = tid >> 6;
  int l = tid & 63;
  int lo = l & 31;
  int hi = l >> 5;
  int b = blockIdx.y;
  int hs = blockIdx.x * 4;  // layer-B output rows hs..hs+3
  int w = wi * 32 + lo;     // this lane's pixel column
  const size_t img = (size_t)b * (HH * WW);

  const int* fA32 = (const int*)fragA;
  for (int i = tid; i < 2304; i += 512) lbf[i] = fA32[i];
  __syncthreads();

  auto ldrow = [&](int yy, int dx) -> i32x4 {
    i32x4 r = {};
    int xx = w + dx - 1;
    if (((unsigned)yy < 256u) && ((unsigned)xx < 256u))
      r = *(const i32x4*)(in + ((img + (size_t)yy * WW + xx) << 5) + hi * 16);
    return r;
  };

  // ---- phase 1: layer A rows hs-1..hs+4 (rrel 0..5), 3 pairs ----
#pragma unroll 1
  for (int p = 0; p < 3; ++p) {
    int aro0 = hs - 1 + 2 * p;  // first A-output row of this pair
    i32x4 rin[4][3];
#pragma unroll
    for (int rr = 0; rr < 4; ++rr)
#pragma unroll
      for (int dx = 0; dx < 3; ++dx)
        rin[rr][dx] = ldrow(aro0 - 1 + rr, dx);

    int pz = 0;
    asm volatile("" : "+v"(pz));  // force per-pair LDS weight re-read
    i32x16 acc0 = {}, acc1 = {};
#pragma unroll
    for (int t = 0; t < 9; ++t) {
      int dy = t / 3, dx = t % 3;
      i32x4 bfv = *(const i32x4*)&lbf[(t * 64 + l) * 4 + pz];
      acc0 = __builtin_amdgcn_mfma_i32_32x32x32_i8(bfv, rin[dy][dx], acc0, 0, 0, 0);
      acc1 = __builtin_amdgcn_mfma_i32_32x32x32_i8(bfv, rin[dy + 1][dx], acc1, 0, 0, 0);
    }
    // write rrel=2p (acc0), 2p+1 (acc1); dword d=2g+hi of pixel w goes to
    // Lint[((rrel*2 + (d>>2))*256 + w)*4 + (d&3)]
#pragma unroll
    for (int g = 0; g < 4; ++g) {
      int d = 2 * g + hi;
      int v0 = pack4(quant1(acc0[4 * g]), quant1(acc0[4 * g + 1]),
                     quant1(acc0[4 * g + 2]), quant1(acc0[4 * g + 3]));
      int v1 = pack4(quant1(acc1[4 * g]), quant1(acc1[4 * g + 1]),
                     quant1(acc1[4 * g + 2]), quant1(acc1[4 * g + 3]));
      Lint[(((2 * p) * 2 + (d >> 2)) * 256 + w) * 4 + (d & 3)] = v0;
      Lint[(((2 * p + 1) * 2 + (d >> 2)) * 256 + w) * 4 + (d & 3)] = v1;
    }
  }

  __syncthreads();
  const int* fB32 = (const int*)fragB;
  for (int i = tid; i < 2304; i += 512) lbf[i] = fB32[i];
  __syncthreads();

  // ---- phase 2: layer B rows hs..hs+3 from LDS, 2 pairs ----
  int mymax = -128;
#pragma unroll 1
  for (int p = 0; p < 2; ++p) {
    i32x4 tp[4][3];
#pragma unroll
    for (int rr = 0; rr < 4; ++rr) {
      int rrel = 2 * p + rr;
      int aro = hs - 1 + rrel;  // absolute layer-A row
#pragma unroll
      for (int dx = 0; dx < 3; ++dx) {
        int px = w + dx - 1;
        i32x4 v = {};
        if (((unsigned)aro < 256u) && ((unsigned)px < 256u))
          v = *(const i32x4*)&Lint[((rrel * 2 + hi) * 256 + px) * 4];
        tp[rr][dx] = v;
      }
    }
    int pz = 0;
    asm volatile("" : "+v"(pz));
    i32x16 acc0 = {}, acc1 = {};
#pragma unroll
    for (int t = 0; t < 9; ++t) {
      int dy = t / 3, dx = t % 3;
      i32x4 bfv = *(const i32x4*)&lbf[(t * 64 + l) * 4 + pz];
      if (MODE == 1) {
        acc0 = __builtin_amdgcn_mfma_i32_32x32x32_i8(tp[dy][dx], bfv, acc0, 0, 0, 0);
        acc1 = __builtin_amdgcn_mfma_i32_32x32x32_i8(tp[dy + 1][dx], bfv, acc1, 0, 0, 0);
      } else {
        acc0 = __builtin_amdgcn_mfma_i32_32x32x32_i8(bfv, tp[dy][dx], acc0, 0, 0, 0);
        acc1 = __builtin_amdgcn_mfma_i32_32x32x32_i8(bfv, tp[dy + 1][dx], acc1, 0, 0, 0);
      }
    }
    if (MODE == 0) {
      // lane owns px=w; dword d=2g+hi of rows hs+2p, hs+2p+1
      int* o32 = (int*)out;
      size_t base = (img + (size_t)(hs + 2 * p) * WW + w) * 8;
#pragma unroll
      for (int g = 0; g < 4; ++g) {
        int v0 = pack4(quant1(acc0[4 * g]), quant1(acc0[4 * g + 1]),
                       quant1(acc0[4 * g + 2]), quant1(acc0[4 * g + 3]));
        int v1 = pack4(quant1(acc1[4 * g]), quant1(acc1[4 * g + 1]),
                       quant1(acc1[4 * g + 2]), quant1(acc1[4 * g + 3]));
        o32[base + 2 * g + hi] = v0;
        o32[base + 2048 + 2 * g + hi] = v1;
      }
    } else {
      mymax = quant_max(acc1, quant_max(acc0, mymax));
    }
  }

  if (MODE == 1) {
    mymax = max(mymax, __shfl_xor(mymax, 32));  // lanes lo & lo+32: same oc
    if (hi == 0) red[wi][lo] = mymax;
    __syncthreads();
    if (tid < 32) {
      int m = -128;
#pragma unroll
      for (int r = 0; r < 8; ++r) m = max(m, red[r][tid]);
      atomicMax(&gmax[b * 32 + tid], m);
    }
  }
}

// ================= final FC =================
__global__ void fc_kernel(const int* __restrict__ gmax, const int* __restrict__ wfcq,
                          float* __restrict__ out) {
  int b = threadIdx.x;
  if (b < BB) {
    int acc = 0;
#pragma unroll
    for (int c = 0; c < 32; ++c) acc += gmax[b * 32 + c] * wfcq[c];
    int q = (int)rintf((float)acc * 0.0078125f);  // rne(acc/128), exact
    q = min(127, max(-127, q));
    out[b] = (float)q * 0.0078125f;
  }
}

extern "C" void kernel_launch(void* const* d_in, const int* in_sizes, int n_in,
                              void* d_out, int out_size, void* d_ws, size_t ws_size,
                              hipStream_t stream) {
  const float* x   = (const float*)d_in[0];
  const float* w1  = (const float*)d_in[1];
  const float* wfc = (const float*)d_in[8];

  char* ws = (char*)d_ws;
  const size_t ACTB = (size_t)BB * HH * WW * 32;  // 33,554,432 B
  signed char* A0    = (signed char*)ws;
  signed char* A1    = (signed char*)(ws + ACTB);
  _Float16*    pre   = (_Float16*)A1;  // dead before F0 writes A1
  _Float16*    frag1 = (_Float16*)(ws + 2 * ACTB);                 // 6144 B
  signed char* wfr   = (signed char*)(ws + 2 * ACTB + 6144);       // 6 x 9216
  int*         wfcq  = (int*)(ws + 2 * ACTB + 6144 + 6 * 9216);
  int*         gmax  = (int*)(ws + 2 * ACTB + 6144 + 6 * 9216 + 128);

  prep_kernel<<<4313, 256, 0, stream>>>(
      x, w1, (const float*)d_in[2], (const float*)d_in[3], (const float*)d_in[4],
      (const float*)d_in[5], (const float*)d_in[6], (const float*)d_in[7],
      wfc, pre, frag1, wfr, wfcq, gmax);

  dim3 gridc1(2, 128, 16);  // conv1: 2-row pairs
  conv1_mfma_kernel<<<gridc1, 256, 0, stream>>>(pre, frag1, A0);

  dim3 gf(64, 16);  // fused pairs: 4-row chunks, full width
  conv_fused_kernel<0><<<gf, 512, 0, stream>>>(A0, wfr + 0 * 9216, wfr + 1 * 9216, A1, nullptr);
  conv_fused_kernel<0><<<gf, 512, 0, stream>>>(A1, wfr + 2 * 9216, wfr + 3 * 9216, A0, nullptr);
  conv_fused_kernel<1><<<gf, 512, 0, stream>>>(A0, wfr + 4 * 9216, wfr + 5 * 9216, nullptr, gmax);
  fc_kernel<<<1, 64, 0, stream>>>(gmax, wfcq, (float*)d_out);
}